// Round 1
// baseline (1776.903 us; speedup 1.0000x reference)
//
#include <hip/hip_runtime.h>
#include <type_traits>

typedef __bf16 bf16;
typedef __bf16 bf16x8 __attribute__((ext_vector_type(8)));
typedef __bf16 bf16x4 __attribute__((ext_vector_type(4)));
typedef float floatx4 __attribute__((ext_vector_type(4)));

#define MFMA16(a, b, c) __builtin_amdgcn_mfma_f32_16x16x32_bf16(a, b, c, 0, 0, 0)

// ---------------------------------------------------------------------------
// Generic NT GEMM: C[m][n] = epi( sum_k A[m][k] * B[n][k] )
// A: (M,K) row-major (fp32 or bf16). B: (N,K) row-major fp32.
// 128x128 tile, BK=64, 256 threads (4 waves, 2x2 of 64x64).
// EPI: 0 = silu -> bf16, 1 = sigmoid -> bf16, 2 = identity -> fp32
// ---------------------------------------------------------------------------
template <int EPI, typename TA>
__global__ __launch_bounds__(256) void gemm_nt(const TA* __restrict__ A,
                                               const float* __restrict__ B,
                                               void* __restrict__ Cv,
                                               int N, long K) {
  __shared__ bf16 As[128][72];  // +8 pad: conflict-free b128 reads
  __shared__ bf16 Bs[128][72];
  const int tid = threadIdx.x;
  const int bm = blockIdx.y, bn = blockIdx.x;
  const int wave = tid >> 6, lane = tid & 63;
  const int quad = lane >> 4, l16 = lane & 15;
  const int wm = (wave & 1) * 64, wn = (wave >> 1) * 64;
  floatx4 acc[4][4] = {};
  const long nkb = K >> 6;
  for (long kb = 0; kb < nkb; ++kb) {
    // stage A tile (128 x 64)
    if constexpr (std::is_same<TA, float>::value) {
#pragma unroll
      for (int i = 0; i < 8; ++i) {
        int idx = tid + i * 256;
        int row = idx >> 4, c4 = (idx & 15) << 2;
        float4 v = *(const float4*)&A[(long)(bm * 128 + row) * K + kb * 64 + c4];
        bf16x4 p = {(bf16)v.x, (bf16)v.y, (bf16)v.z, (bf16)v.w};
        *(bf16x4*)&As[row][c4] = p;
      }
    } else {
#pragma unroll
      for (int i = 0; i < 4; ++i) {
        int idx = tid + i * 256;
        int row = idx >> 3, c8 = (idx & 7) << 3;
        *(bf16x8*)&As[row][c8] =
            *(const bf16x8*)&A[(long)(bm * 128 + row) * K + kb * 64 + c8];
      }
    }
    // stage B tile (128 x 64), fp32 -> bf16
#pragma unroll
    for (int i = 0; i < 8; ++i) {
      int idx = tid + i * 256;
      int row = idx >> 4, c4 = (idx & 15) << 2;
      float4 v = *(const float4*)&B[(long)(bn * 128 + row) * K + kb * 64 + c4];
      bf16x4 p = {(bf16)v.x, (bf16)v.y, (bf16)v.z, (bf16)v.w};
      *(bf16x4*)&Bs[row][c4] = p;
    }
    __syncthreads();
#pragma unroll
    for (int ks = 0; ks < 2; ++ks) {
      bf16x8 af[4], bfr[4];
#pragma unroll
      for (int mt = 0; mt < 4; ++mt)
        af[mt] = *(const bf16x8*)&As[wm + mt * 16 + l16][ks * 32 + quad * 8];
#pragma unroll
      for (int nt = 0; nt < 4; ++nt)
        bfr[nt] = *(const bf16x8*)&Bs[wn + nt * 16 + l16][ks * 32 + quad * 8];
#pragma unroll
      for (int mt = 0; mt < 4; ++mt)
#pragma unroll
        for (int nt = 0; nt < 4; ++nt)
          acc[mt][nt] = MFMA16(af[mt], bfr[nt], acc[mt][nt]);
    }
    __syncthreads();
  }
#pragma unroll
  for (int mt = 0; mt < 4; ++mt)
#pragma unroll
    for (int nt = 0; nt < 4; ++nt)
#pragma unroll
      for (int r = 0; r < 4; ++r) {
        const int row = bm * 128 + wm + mt * 16 + quad * 4 + r;
        const int col = bn * 128 + wn + nt * 16 + l16;
        const float v = acc[mt][nt][r];
        if constexpr (EPI == 0) {
          ((bf16*)Cv)[(long)row * N + col] = (bf16)(v / (1.f + __expf(-v)));
        } else if constexpr (EPI == 1) {
          ((bf16*)Cv)[(long)row * N + col] = (bf16)(1.f / (1.f + __expf(-v)));
        } else {
          ((float*)Cv)[(long)row * N + col] = v;
        }
      }
}

// ---------------------------------------------------------------------------
// Build kT[h][d][t] and vT[h][e][t] (bf16) from qkvb[t][h*384 + {128+d, 256+e}]
// grid (64 t-tiles, 4 quadrants: 0,1=k halves 2,3=v halves, 32 heads), 256 thr
// ---------------------------------------------------------------------------
__global__ __launch_bounds__(256) void transpose_kv(const bf16* __restrict__ qkvb,
                                                    bf16* __restrict__ kT,
                                                    bf16* __restrict__ vT) {
  __shared__ bf16 tile[64][72];
  const int tid = threadIdx.x;
  const int t0 = blockIdx.x * 64;
  const int qz = blockIdx.y;
  const int h = blockIdx.z;
  const int srccol = h * 384 + 128 + (qz >> 1) * 128 + (qz & 1) * 64;
  const int row = tid >> 2, cb = (tid & 3) * 16;
#pragma unroll
  for (int i = 0; i < 2; ++i)
    *(bf16x8*)&tile[row][cb + i * 8] =
        *(const bf16x8*)&qkvb[(long)(t0 + row) * 12288 + srccol + cb + i * 8];
  __syncthreads();
  bf16* dst = (qz >= 2) ? vT : kT;
  const int ch = (qz & 1) * 64 + (tid >> 2);
#pragma unroll
  for (int i = 0; i < 2; ++i) {
    bf16x8 v;
#pragma unroll
    for (int j = 0; j < 8; ++j) v[j] = tile[cb + i * 8 + j][tid >> 2];
    *(bf16x8*)&dst[((long)h * 128 + ch) * 4096 + t0 + cb + i * 8] = v;
  }
}

// ---------------------------------------------------------------------------
// Per-(head,block) decayed KV contribution, stored transposed:
// MT[h][b][e][d] = sum_i v[i][e] * (exp(-s*(255-i)) * k[i][d]),  fp32
// grid (16 blocks, 32 heads), 256 threads (4 waves, 2x2 of 64x64)
// ---------------------------------------------------------------------------
__global__ __launch_bounds__(256) void kv_blocks(const bf16* __restrict__ kT,
                                                 const bf16* __restrict__ vT,
                                                 const float* __restrict__ slope,
                                                 float* __restrict__ MT) {
  __shared__ float kdec[256];
  const int tid = threadIdx.x;
  const int b = blockIdx.x, h = blockIdx.y;
  const float s = slope[h];
  if (tid < 256) kdec[tid] = __expf(-s * (float)(255 - tid));
  __syncthreads();
  const int wave = tid >> 6, lane = tid & 63;
  const int quad = lane >> 4, l16 = lane & 15;
  const int we = (wave & 1) * 64, wd = (wave >> 1) * 64;
  floatx4 acc[4][4] = {};
  for (int kc = 0; kc < 8; ++kc) {
    const int ioff = kc * 32 + quad * 8;
    bf16x8 af[4], bfr[4];
#pragma unroll
    for (int mt = 0; mt < 4; ++mt)
      af[mt] = *(const bf16x8*)&vT[((long)h * 128 + we + mt * 16 + l16) * 4096 +
                                   b * 256 + ioff];
#pragma unroll
    for (int nt = 0; nt < 4; ++nt) {
      bf16x8 k8 = *(const bf16x8*)&kT[((long)h * 128 + wd + nt * 16 + l16) * 4096 +
                                      b * 256 + ioff];
      bf16x8 kb;
#pragma unroll
      for (int j = 0; j < 8; ++j) kb[j] = (bf16)((float)k8[j] * kdec[ioff + j]);
      bfr[nt] = kb;
    }
#pragma unroll
    for (int mt = 0; mt < 4; ++mt)
#pragma unroll
      for (int nt = 0; nt < 4; ++nt)
        acc[mt][nt] = MFMA16(af[mt], bfr[nt], acc[mt][nt]);
  }
#pragma unroll
  for (int mt = 0; mt < 4; ++mt)
#pragma unroll
    for (int nt = 0; nt < 4; ++nt)
#pragma unroll
      for (int r = 0; r < 4; ++r) {
        const int e = we + mt * 16 + quad * 4 + r;
        const int d = wd + nt * 16 + l16;
        MT[(((long)h * 16 + b) * 128 + e) * 128 + d] = acc[mt][nt][r];
      }
}

// ---------------------------------------------------------------------------
// Elementwise prefix scan over the 16 blocks:
// ST[h][b][e][d] = KV_b[d][e] (bf16); KV_0 = kv_cache, KV_{b+1}=bd*KV_b + M_b
// ---------------------------------------------------------------------------
__global__ __launch_bounds__(256) void kv_scan(const float* __restrict__ MT,
                                               const float* __restrict__ kvc,
                                               const float* __restrict__ slope,
                                               bf16* __restrict__ ST) {
  const long idx = (long)blockIdx.x * 256 + threadIdx.x;  // (h, e, d), d fastest
  const int d = idx & 127;
  const int e = (int)((idx >> 7) & 127);
  const int h = (int)(idx >> 14);
  const float s = slope[h];
  const float bd = __expf(-s * 256.f);
  float kv = kvc[((long)h * 128 + d) * 128 + e];
#pragma unroll
  for (int b = 0; b < 16; ++b) {
    const long o = (((long)h * 16 + b) * 128 + e) * 128 + d;
    ST[o] = (bf16)kv;
    kv = bd * kv + MT[o];
  }
}

// ---------------------------------------------------------------------------
// Per-(head,block) attention output:
// O[i][e] = q_dec[i]*sum_d q[i][d]*KV_b[d][e]
//         + sum_{j<=i} exp(-s*(i-j)) * (sum_d q[i][d]k[j][d]) * v[j][e]
// grid (16 blocks, 32 heads), 512 threads (8 waves, each 32 rows of i)
// ---------------------------------------------------------------------------
__global__ __launch_bounds__(512) void attn_out(const bf16* __restrict__ qkvb,
                                                const bf16* __restrict__ vT,
                                                const bf16* __restrict__ ST,
                                                const float* __restrict__ slope,
                                                float* __restrict__ hidden) {
  __shared__ float ddt[257];          // ddt[d] = exp(-s*d)
  __shared__ bf16 sbuf[8][32][72];    // per-wave decayed-S staging (C->A layout)
  const int tid = threadIdx.x;
  const int b = blockIdx.x, h = blockIdx.y;
  const float s = slope[h];
  if (tid < 257) ddt[tid] = __expf(-s * (float)tid);
  __syncthreads();
  const int wave = tid >> 6, lane = tid & 63;
  const int quad = lane >> 4, l16 = lane & 15;
  const int iw = wave * 32;
  floatx4 oacc[2][8] = {};
  for (int jb = 0; jb < 4; ++jb) {
    floatx4 sacc[2][4] = {};
#pragma unroll
    for (int kc = 0; kc < 4; ++kc) {
      bf16x8 qf[2], kf[4];
#pragma unroll
      for (int mt = 0; mt < 2; ++mt)
        qf[mt] = *(const bf16x8*)&qkvb[(long)(b * 256 + iw + mt * 16 + l16) * 12288 +
                                       h * 384 + kc * 32 + quad * 8];
#pragma unroll
      for (int nt = 0; nt < 4; ++nt)
        kf[nt] = *(const bf16x8*)&qkvb[(long)(b * 256 + jb * 64 + nt * 16 + l16) * 12288 +
                                       h * 384 + 128 + kc * 32 + quad * 8];
#pragma unroll
      for (int mt = 0; mt < 2; ++mt)
#pragma unroll
        for (int nt = 0; nt < 4; ++nt)
          sacc[mt][nt] = MFMA16(qf[mt], kf[nt], sacc[mt][nt]);
    }
    // decay + causal mask, C-layout -> A-layout via LDS (per-wave region)
#pragma unroll
    for (int mt = 0; mt < 2; ++mt)
#pragma unroll
      for (int nt = 0; nt < 4; ++nt)
#pragma unroll
        for (int r = 0; r < 4; ++r) {
          const int i = iw + mt * 16 + quad * 4 + r;
          const int j = jb * 64 + nt * 16 + l16;
          const int diff = i - j;
          const float v = (diff >= 0) ? sacc[mt][nt][r] * ddt[diff] : 0.f;
          sbuf[wave][mt * 16 + quad * 4 + r][nt * 16 + l16] = (bf16)v;
        }
    __syncthreads();
    // O_intra += S_dec @ v
#pragma unroll
    for (int kc2 = 0; kc2 < 2; ++kc2) {
      bf16x8 sf[2];
#pragma unroll
      for (int mt = 0; mt < 2; ++mt)
        sf[mt] = *(const bf16x8*)&sbuf[wave][mt * 16 + l16][kc2 * 32 + quad * 8];
#pragma unroll
      for (int et = 0; et < 8; ++et) {
        bf16x8 vf = *(const bf16x8*)&vT[((long)h * 128 + et * 16 + l16) * 4096 +
                                        b * 256 + jb * 64 + kc2 * 32 + quad * 8];
#pragma unroll
        for (int mt = 0; mt < 2; ++mt)
          oacc[mt][et] = MFMA16(sf[mt], vf, oacc[mt][et]);
      }
    }
    __syncthreads();
  }
  // O_inter += (q * q_dec) @ KV_b
#pragma unroll
  for (int kc = 0; kc < 4; ++kc) {
    bf16x8 qf[2];
#pragma unroll
    for (int mt = 0; mt < 2; ++mt) {
      bf16x8 q8 = *(const bf16x8*)&qkvb[(long)(b * 256 + iw + mt * 16 + l16) * 12288 +
                                        h * 384 + kc * 32 + quad * 8];
      const float qd = ddt[iw + mt * 16 + l16 + 1];  // exp(-s*(i+1))
      bf16x8 qq;
#pragma unroll
      for (int j = 0; j < 8; ++j) qq[j] = (bf16)((float)q8[j] * qd);
      qf[mt] = qq;
    }
#pragma unroll
    for (int et = 0; et < 8; ++et) {
      bf16x8 kvf = *(const bf16x8*)&ST[(((long)h * 16 + b) * 128 + et * 16 + l16) * 128 +
                                       kc * 32 + quad * 8];
#pragma unroll
      for (int mt = 0; mt < 2; ++mt)
        oacc[mt][et] = MFMA16(qf[mt], kvf, oacc[mt][et]);
    }
  }
#pragma unroll
  for (int mt = 0; mt < 2; ++mt)
#pragma unroll
    for (int et = 0; et < 8; ++et)
#pragma unroll
      for (int r = 0; r < 4; ++r) {
        const int t = b * 256 + iw + mt * 16 + quad * 4 + r;
        const int e = et * 16 + l16;
        hidden[(long)t * 4096 + h * 128 + e] = oacc[mt][et][r];
      }
}

// ---------------------------------------------------------------------------
// Row-wise RMSNorm of hidden, times norm_weight and gate -> bf16 afinal
// grid 4096 rows, 256 threads
// ---------------------------------------------------------------------------
__global__ __launch_bounds__(256) void rms_gate(const float* __restrict__ hidden,
                                                const bf16* __restrict__ gateb,
                                                const float* __restrict__ nw,
                                                bf16* __restrict__ afinal) {
  const int t = blockIdx.x, tid = threadIdx.x;
  const float* rowp = hidden + (long)t * 4096;
  float ss = 0.f;
  float4 hv[4];
#pragma unroll
  for (int i = 0; i < 4; ++i) {
    hv[i] = ((const float4*)rowp)[tid + i * 256];
    ss += hv[i].x * hv[i].x + hv[i].y * hv[i].y + hv[i].z * hv[i].z + hv[i].w * hv[i].w;
  }
#pragma unroll
  for (int off = 32; off > 0; off >>= 1) ss += __shfl_down(ss, off);
  __shared__ float red[4];
  if ((tid & 63) == 0) red[tid >> 6] = ss;
  __syncthreads();
  const float tot = red[0] + red[1] + red[2] + red[3];
  const float rs = rsqrtf(tot * (1.f / 4096.f) + 1e-5f);
#pragma unroll
  for (int i = 0; i < 4; ++i) {
    const int c = (tid + i * 256) * 4;
    bf16x4 g = *(const bf16x4*)&gateb[(long)t * 4096 + c];
    float4 w = *(const float4*)&nw[c];
    bf16x4 o;
    o[0] = (bf16)(hv[i].x * rs * w.x * (float)g[0]);
    o[1] = (bf16)(hv[i].y * rs * w.y * (float)g[1]);
    o[2] = (bf16)(hv[i].z * rs * w.z * (float)g[2]);
    o[3] = (bf16)(hv[i].w * rs * w.w * (float)g[3]);
    *(bf16x4*)&afinal[(long)t * 4096 + c] = o;
  }
}

// ---------------------------------------------------------------------------
extern "C" void kernel_launch(void* const* d_in, const int* in_sizes, int n_in,
                              void* d_out, int out_size, void* d_ws, size_t ws_size,
                              hipStream_t stream) {
  (void)in_sizes; (void)n_in; (void)out_size;
  const float* x      = (const float*)d_in[0];
  const float* w_qkv  = (const float*)d_in[1];
  const float* w_gate = (const float*)d_in[2];
  const float* w_out  = (const float*)d_in[3];
  const float* nw     = (const float*)d_in[4];
  const float* kvc    = (const float*)d_in[5];
  const float* slope  = (const float*)d_in[6];
  float* out = (float*)d_out;

  char* p = (char*)d_ws;
  bf16* qkvb = (bf16*)p;    p += (size_t)4096 * 12288 * 2;       // 96 MB
  bf16* kT = (bf16*)p;      p += (size_t)32 * 128 * 4096 * 2;    // 32 MB
  bf16* vT = (bf16*)p;      p += (size_t)32 * 128 * 4096 * 2;    // 32 MB
  float* MT = (float*)p;    p += (size_t)32 * 16 * 128 * 128 * 4;// 32 MB
  bf16* ST = (bf16*)p;      p += (size_t)32 * 16 * 128 * 128 * 2;// 16 MB
  float* hidden = (float*)p;p += (size_t)4096 * 4096 * 4;        // 64 MB
  bf16* gateb = (bf16*)p;   p += (size_t)4096 * 4096 * 2;        // 32 MB
  bf16* afinal = (bf16*)p;  p += (size_t)4096 * 4096 * 2;        // 32 MB
  if ((size_t)(p - (char*)d_ws) > ws_size) return;  // ws too small: clean fail

  // 1) qkv = silu(x @ w_qkv^T), bf16
  gemm_nt<0, float><<<dim3(96, 32), 256, 0, stream>>>(x, w_qkv, qkvb, 12288, 4096);
  // 2) k^T, v^T per head
  transpose_kv<<<dim3(64, 4, 32), 256, 0, stream>>>(qkvb, kT, vT);
  // 3) per-block decayed KV contributions (parallel over head,block)
  kv_blocks<<<dim3(16, 32), 256, 0, stream>>>(kT, vT, slope, MT);
  // 4) sequential-in-b elementwise scan -> per-block KV states (bf16, [e][d])
  kv_scan<<<dim3(2048), 256, 0, stream>>>(MT, kvc, slope, ST);
  // 5) gate = sigmoid(x @ w_gate^T), bf16
  gemm_nt<1, float><<<dim3(32, 32), 256, 0, stream>>>(x, w_gate, gateb, 4096, 4096);
  // 6) attention outputs -> hidden (fp32, [t][h*128+e])
  attn_out<<<dim3(16, 32), 512, 0, stream>>>(qkvb, vT, ST, slope, hidden);
  // 7) RMSNorm * norm_weight * gate -> bf16
  rms_gate<<<dim3(4096), 256, 0, stream>>>(hidden, gateb, nw, afinal);
  // 8) out = afinal @ w_out^T, fp32
  gemm_nt<2, __bf16><<<dim3(32, 32), 256, 0, stream>>>(afinal, w_out, out, 4096, 4096);
}

// Round 2
// 1654.960 us; speedup vs baseline: 1.0737x; 1.0737x over previous
//
#include <hip/hip_runtime.h>

typedef __bf16 bf16;
typedef __bf16 bf16x8 __attribute__((ext_vector_type(8)));
typedef __bf16 bf16x4 __attribute__((ext_vector_type(4)));
typedef float floatx4 __attribute__((ext_vector_type(4)));

#define MFMA16(a, b, c) __builtin_amdgcn_mfma_f32_16x16x32_bf16(a, b, c, 0, 0, 0)

// async global->LDS, 16 bytes/lane, dest = wave-uniform base + lane*16
#define GLOAD_LDS16(g, l)                                          \
  __builtin_amdgcn_global_load_lds(                                \
      (const __attribute__((address_space(1))) void*)(g),          \
      (__attribute__((address_space(3))) void*)(l), 16, 0, 0)

// ---------------------------------------------------------------------------
// fp32 -> bf16 elementwise convert (8 elems/thread)
// ---------------------------------------------------------------------------
__global__ __launch_bounds__(256) void cvt_bf16(const float* __restrict__ src,
                                                bf16* __restrict__ dst, long n) {
  const long i = ((long)blockIdx.x * 256 + threadIdx.x) * 8;
  if (i >= n) return;
  float4 a = *(const float4*)&src[i];
  float4 b = *(const float4*)&src[i + 4];
  bf16x8 o = {(bf16)a.x, (bf16)a.y, (bf16)a.z, (bf16)a.w,
              (bf16)b.x, (bf16)b.y, (bf16)b.z, (bf16)b.w};
  *(bf16x8*)&dst[i] = o;
}

// ---------------------------------------------------------------------------
// m97-style NT GEMM: C[m][n] = epi( sum_k A[m][k] * B[n][k] ), A,B bf16.
// 128x128 tile, BK=64, 256 threads (4 waves, 2x2 of 64x64 quadrants).
// Staging via global_load_lds width=16, unpadded LDS tiles [128][64].
// EPI: 0 = silu -> bf16, 1 = sigmoid -> bf16, 2 = identity -> fp32
// ---------------------------------------------------------------------------
template <int EPI>
__global__ __launch_bounds__(256) void gemm_lds(const bf16* __restrict__ A,
                                                const bf16* __restrict__ B,
                                                void* __restrict__ Cv,
                                                int N, int K) {
  __shared__ bf16 As[128 * 64];
  __shared__ bf16 Bs[128 * 64];
  const int tid = threadIdx.x;
  const int wave = tid >> 6, lane = tid & 63;
  const int quad = lane >> 4, l16 = lane & 15;
  const int bm = blockIdx.y, bn = blockIdx.x;
  const int wm = (wave & 1) * 64, wn = (wave >> 1) * 64;
  // staging: wave w covers rows [w*32, w*32+32) in 4 chunks of 8 rows;
  // lane i -> row chunkbase + i/8, cols (i%8)*8 .. +8  (16 B)
  const int srow = lane >> 3;
  const int scol = (lane & 7) * 8;
  const long arow = (long)(bm * 128 + wave * 32 + srow);
  const long brow = (long)(bn * 128 + wave * 32 + srow);
  const bf16* ga = A + arow * K + scol;
  const bf16* gb = B + brow * K + scol;
  bf16* lsa = &As[(wave * 32 + srow * 0) * 64];  // wave-uniform base
  bf16* lsb = &Bs[(wave * 32) * 64];
  floatx4 acc[4][4] = {};
  for (int kb = 0; kb < K; kb += 64) {
#pragma unroll
    for (int c = 0; c < 4; ++c) {
      GLOAD_LDS16(ga + (long)c * 8 * K + kb, &As[(wave * 32 + c * 8) * 64]);
      GLOAD_LDS16(gb + (long)c * 8 * K + kb, &Bs[(wave * 32 + c * 8) * 64]);
    }
    __syncthreads();
#pragma unroll
    for (int ks = 0; ks < 2; ++ks) {
      bf16x8 af[4], bfr[4];
#pragma unroll
      for (int mt = 0; mt < 4; ++mt)
        af[mt] = *(const bf16x8*)&As[(wm + mt * 16 + l16) * 64 + ks * 32 + quad * 8];
#pragma unroll
      for (int nt = 0; nt < 4; ++nt)
        bfr[nt] = *(const bf16x8*)&Bs[(wn + nt * 16 + l16) * 64 + ks * 32 + quad * 8];
#pragma unroll
      for (int mt = 0; mt < 4; ++mt)
#pragma unroll
        for (int nt = 0; nt < 4; ++nt)
          acc[mt][nt] = MFMA16(af[mt], bfr[nt], acc[mt][nt]);
    }
    __syncthreads();
  }
  (void)lsa; (void)lsb;
#pragma unroll
  for (int mt = 0; mt < 4; ++mt)
#pragma unroll
    for (int nt = 0; nt < 4; ++nt)
#pragma unroll
      for (int r = 0; r < 4; ++r) {
        const int row = bm * 128 + wm + mt * 16 + quad * 4 + r;
        const int col = bn * 128 + wn + nt * 16 + l16;
        const float v = acc[mt][nt][r];
        if constexpr (EPI == 0) {
          ((bf16*)Cv)[(long)row * N + col] = (bf16)(v / (1.f + __expf(-v)));
        } else if constexpr (EPI == 1) {
          ((bf16*)Cv)[(long)row * N + col] = (bf16)(1.f / (1.f + __expf(-v)));
        } else {
          ((float*)Cv)[(long)row * N + col] = v;
        }
      }
}

// ---------------------------------------------------------------------------
// Build kT[h][d][t] and vT[h][e][t] (bf16) from qkvb[t][h*384 + {128+d, 256+e}]
// ---------------------------------------------------------------------------
__global__ __launch_bounds__(256) void transpose_kv(const bf16* __restrict__ qkvb,
                                                    bf16* __restrict__ kT,
                                                    bf16* __restrict__ vT) {
  __shared__ bf16 tile[64][72];
  const int tid = threadIdx.x;
  const int t0 = blockIdx.x * 64;
  const int qz = blockIdx.y;
  const int h = blockIdx.z;
  const int srccol = h * 384 + 128 + (qz >> 1) * 128 + (qz & 1) * 64;
  const int row = tid >> 2, cb = (tid & 3) * 16;
#pragma unroll
  for (int i = 0; i < 2; ++i)
    *(bf16x8*)&tile[row][cb + i * 8] =
        *(const bf16x8*)&qkvb[(long)(t0 + row) * 12288 + srccol + cb + i * 8];
  __syncthreads();
  bf16* dst = (qz >= 2) ? vT : kT;
  const int ch = (qz & 1) * 64 + (tid >> 2);
#pragma unroll
  for (int i = 0; i < 2; ++i) {
    bf16x8 v;
#pragma unroll
    for (int j = 0; j < 8; ++j) v[j] = tile[cb + i * 8 + j][tid >> 2];
    *(bf16x8*)&dst[((long)h * 128 + ch) * 4096 + t0 + cb + i * 8] = v;
  }
}

// ---------------------------------------------------------------------------
// MT[h][b][e][d] = sum_i v[i][e] * (exp(-s*(255-i)) * k[i][d]),  fp32
// ---------------------------------------------------------------------------
__global__ __launch_bounds__(256) void kv_blocks(const bf16* __restrict__ kT,
                                                 const bf16* __restrict__ vT,
                                                 const float* __restrict__ slope,
                                                 float* __restrict__ MT) {
  __shared__ float kdec[256];
  const int tid = threadIdx.x;
  const int b = blockIdx.x, h = blockIdx.y;
  const float s = slope[h];
  if (tid < 256) kdec[tid] = __expf(-s * (float)(255 - tid));
  __syncthreads();
  const int wave = tid >> 6, lane = tid & 63;
  const int quad = lane >> 4, l16 = lane & 15;
  const int we = (wave & 1) * 64, wd = (wave >> 1) * 64;
  floatx4 acc[4][4] = {};
  for (int kc = 0; kc < 8; ++kc) {
    const int ioff = kc * 32 + quad * 8;
    bf16x8 af[4], bfr[4];
#pragma unroll
    for (int mt = 0; mt < 4; ++mt)
      af[mt] = *(const bf16x8*)&vT[((long)h * 128 + we + mt * 16 + l16) * 4096 +
                                   b * 256 + ioff];
#pragma unroll
    for (int nt = 0; nt < 4; ++nt) {
      bf16x8 k8 = *(const bf16x8*)&kT[((long)h * 128 + wd + nt * 16 + l16) * 4096 +
                                      b * 256 + ioff];
      bf16x8 kb;
#pragma unroll
      for (int j = 0; j < 8; ++j) kb[j] = (bf16)((float)k8[j] * kdec[ioff + j]);
      bfr[nt] = kb;
    }
#pragma unroll
    for (int mt = 0; mt < 4; ++mt)
#pragma unroll
      for (int nt = 0; nt < 4; ++nt)
        acc[mt][nt] = MFMA16(af[mt], bfr[nt], acc[mt][nt]);
  }
#pragma unroll
  for (int mt = 0; mt < 4; ++mt)
#pragma unroll
    for (int nt = 0; nt < 4; ++nt)
#pragma unroll
      for (int r = 0; r < 4; ++r) {
        const int e = we + mt * 16 + quad * 4 + r;
        const int d = wd + nt * 16 + l16;
        MT[(((long)h * 16 + b) * 128 + e) * 128 + d] = acc[mt][nt][r];
      }
}

// ---------------------------------------------------------------------------
// ST[h][b][e][d] = KV_b[d][e] (bf16); KV_0 = kv_cache, KV_{b+1}=bd*KV_b + M_b
// ---------------------------------------------------------------------------
__global__ __launch_bounds__(256) void kv_scan(const float* __restrict__ MT,
                                               const float* __restrict__ kvc,
                                               const float* __restrict__ slope,
                                               bf16* __restrict__ ST) {
  const long idx = (long)blockIdx.x * 256 + threadIdx.x;
  const int d = idx & 127;
  const int e = (int)((idx >> 7) & 127);
  const int h = (int)(idx >> 14);
  const float s = slope[h];
  const float bd = __expf(-s * 256.f);
  float kv = kvc[((long)h * 128 + d) * 128 + e];
#pragma unroll
  for (int b = 0; b < 16; ++b) {
    const long o = (((long)h * 16 + b) * 128 + e) * 128 + d;
    ST[o] = (bf16)kv;
    kv = bd * kv + MT[o];
  }
}

// ---------------------------------------------------------------------------
// Per-(head,block) attention output -> hidden fp32 [t][h*128+e]
// ---------------------------------------------------------------------------
__global__ __launch_bounds__(512) void attn_out(const bf16* __restrict__ qkvb,
                                                const bf16* __restrict__ vT,
                                                const bf16* __restrict__ ST,
                                                const float* __restrict__ slope,
                                                float* __restrict__ hidden) {
  __shared__ float ddt[257];
  __shared__ bf16 sbuf[8][32][72];
  const int tid = threadIdx.x;
  const int b = blockIdx.x, h = blockIdx.y;
  const float s = slope[h];
  if (tid < 257) ddt[tid] = __expf(-s * (float)tid);
  __syncthreads();
  const int wave = tid >> 6, lane = tid & 63;
  const int quad = lane >> 4, l16 = lane & 15;
  const int iw = wave * 32;
  floatx4 oacc[2][8] = {};
  for (int jb = 0; jb < 4; ++jb) {
    floatx4 sacc[2][4] = {};
#pragma unroll
    for (int kc = 0; kc < 4; ++kc) {
      bf16x8 qf[2], kf[4];
#pragma unroll
      for (int mt = 0; mt < 2; ++mt)
        qf[mt] = *(const bf16x8*)&qkvb[(long)(b * 256 + iw + mt * 16 + l16) * 12288 +
                                       h * 384 + kc * 32 + quad * 8];
#pragma unroll
      for (int nt = 0; nt < 4; ++nt)
        kf[nt] = *(const bf16x8*)&qkvb[(long)(b * 256 + jb * 64 + nt * 16 + l16) * 12288 +
                                       h * 384 + 128 + kc * 32 + quad * 8];
#pragma unroll
      for (int mt = 0; mt < 2; ++mt)
#pragma unroll
        for (int nt = 0; nt < 4; ++nt)
          sacc[mt][nt] = MFMA16(qf[mt], kf[nt], sacc[mt][nt]);
    }
#pragma unroll
    for (int mt = 0; mt < 2; ++mt)
#pragma unroll
      for (int nt = 0; nt < 4; ++nt)
#pragma unroll
        for (int r = 0; r < 4; ++r) {
          const int i = iw + mt * 16 + quad * 4 + r;
          const int j = jb * 64 + nt * 16 + l16;
          const int diff = i - j;
          const float v = (diff >= 0) ? sacc[mt][nt][r] * ddt[diff] : 0.f;
          sbuf[wave][mt * 16 + quad * 4 + r][nt * 16 + l16] = (bf16)v;
        }
    __syncthreads();
#pragma unroll
    for (int kc2 = 0; kc2 < 2; ++kc2) {
      bf16x8 sf[2];
#pragma unroll
      for (int mt = 0; mt < 2; ++mt)
        sf[mt] = *(const bf16x8*)&sbuf[wave][mt * 16 + l16][kc2 * 32 + quad * 8];
#pragma unroll
      for (int et = 0; et < 8; ++et) {
        bf16x8 vf = *(const bf16x8*)&vT[((long)h * 128 + et * 16 + l16) * 4096 +
                                        b * 256 + jb * 64 + kc2 * 32 + quad * 8];
#pragma unroll
        for (int mt = 0; mt < 2; ++mt)
          oacc[mt][et] = MFMA16(sf[mt], vf, oacc[mt][et]);
      }
    }
    __syncthreads();
  }
#pragma unroll
  for (int kc = 0; kc < 4; ++kc) {
    bf16x8 qf[2];
#pragma unroll
    for (int mt = 0; mt < 2; ++mt) {
      bf16x8 q8 = *(const bf16x8*)&qkvb[(long)(b * 256 + iw + mt * 16 + l16) * 12288 +
                                        h * 384 + kc * 32 + quad * 8];
      const float qd = ddt[iw + mt * 16 + l16 + 1];
      bf16x8 qq;
#pragma unroll
      for (int j = 0; j < 8; ++j) qq[j] = (bf16)((float)q8[j] * qd);
      qf[mt] = qq;
    }
#pragma unroll
    for (int et = 0; et < 8; ++et) {
      bf16x8 kvf = *(const bf16x8*)&ST[(((long)h * 16 + b) * 128 + et * 16 + l16) * 128 +
                                       kc * 32 + quad * 8];
#pragma unroll
      for (int mt = 0; mt < 2; ++mt)
        oacc[mt][et] = MFMA16(qf[mt], kvf, oacc[mt][et]);
    }
  }
#pragma unroll
  for (int mt = 0; mt < 2; ++mt)
#pragma unroll
    for (int et = 0; et < 8; ++et)
#pragma unroll
      for (int r = 0; r < 4; ++r) {
        const int t = b * 256 + iw + mt * 16 + quad * 4 + r;
        const int e = et * 16 + l16;
        hidden[(long)t * 4096 + h * 128 + e] = oacc[mt][et][r];
      }
}

// ---------------------------------------------------------------------------
// RMSNorm * norm_weight * gate -> bf16
// ---------------------------------------------------------------------------
__global__ __launch_bounds__(256) void rms_gate(const float* __restrict__ hidden,
                                                const bf16* __restrict__ gateb,
                                                const float* __restrict__ nw,
                                                bf16* __restrict__ afinal) {
  const int t = blockIdx.x, tid = threadIdx.x;
  const float* rowp = hidden + (long)t * 4096;
  float ss = 0.f;
  float4 hv[4];
#pragma unroll
  for (int i = 0; i < 4; ++i) {
    hv[i] = ((const float4*)rowp)[tid + i * 256];
    ss += hv[i].x * hv[i].x + hv[i].y * hv[i].y + hv[i].z * hv[i].z + hv[i].w * hv[i].w;
  }
#pragma unroll
  for (int off = 32; off > 0; off >>= 1) ss += __shfl_down(ss, off);
  __shared__ float red[4];
  if ((tid & 63) == 0) red[tid >> 6] = ss;
  __syncthreads();
  const float tot = red[0] + red[1] + red[2] + red[3];
  const float rs = rsqrtf(tot * (1.f / 4096.f) + 1e-5f);
#pragma unroll
  for (int i = 0; i < 4; ++i) {
    const int c = (tid + i * 256) * 4;
    bf16x4 g = *(const bf16x4*)&gateb[(long)t * 4096 + c];
    float4 w = *(const float4*)&nw[c];
    bf16x4 o;
    o[0] = (bf16)(hv[i].x * rs * w.x * (float)g[0]);
    o[1] = (bf16)(hv[i].y * rs * w.y * (float)g[1]);
    o[2] = (bf16)(hv[i].z * rs * w.z * (float)g[2]);
    o[3] = (bf16)(hv[i].w * rs * w.w * (float)g[3]);
    *(bf16x4*)&afinal[(long)t * 4096 + c] = o;
  }
}

// ---------------------------------------------------------------------------
extern "C" void kernel_launch(void* const* d_in, const int* in_sizes, int n_in,
                              void* d_out, int out_size, void* d_ws, size_t ws_size,
                              hipStream_t stream) {
  (void)in_sizes; (void)n_in; (void)out_size;
  const float* x      = (const float*)d_in[0];
  const float* w_qkv  = (const float*)d_in[1];
  const float* w_gate = (const float*)d_in[2];
  const float* w_out  = (const float*)d_in[3];
  const float* nw     = (const float*)d_in[4];
  const float* kvc    = (const float*)d_in[5];
  const float* slope  = (const float*)d_in[6];
  float* out = (float*)d_out;

  const size_t MB = 1024 * 1024;
  char* base = (char*)d_ws;
  // 384 MB total with aliasing (stream order guarantees safety):
  bf16* qkvb   = (bf16*)(base + 0 * MB);     // 96 MB,  live steps 2..7
  bf16* kT     = (bf16*)(base + 96 * MB);    // 32 MB
  bf16* vT     = (bf16*)(base + 128 * MB);   // 32 MB
  bf16* wob    = (bf16*)(base + 160 * MB);   // 32 MB, live 1..9
  bf16* gateb  = (bf16*)(base + 192 * MB);   // 32 MB, live 3..8
  bf16* xb     = (bf16*)(base + 224 * MB);   // 32 MB, live 1..3
  bf16* afinal = (bf16*)(base + 224 * MB);   // aliases xb (live 8..9)
  bf16* wb     = (bf16*)(base + 256 * MB);   // 128 MB, live 1..3
  float* MT    = (float*)(base + 256 * MB);  // aliases wb (live 5..6)
  bf16* ST     = (bf16*)(base + 288 * MB);   // aliases wb (live 6..7)
  float* hidden= (float*)(base + 304 * MB);  // aliases wb (live 7..8), 64 MB
  if (ws_size < 384 * MB) return;  // clean fail -> visible as absmax blowup

  const long nx = 4096L * 4096, nqkv = 12288L * 4096;
  // 1) fp32 -> bf16 converts
  cvt_bf16<<<dim3((int)(nx / 2048)), 256, 0, stream>>>(x, xb, nx);
  cvt_bf16<<<dim3((int)(nqkv / 2048)), 256, 0, stream>>>(w_qkv, wb, nqkv);
  cvt_bf16<<<dim3((int)(nx / 2048)), 256, 0, stream>>>(w_gate, wb + nqkv, nx);
  cvt_bf16<<<dim3((int)(nx / 2048)), 256, 0, stream>>>(w_out, wob, nx);
  // 2) qkv = silu(x @ w_qkv^T), bf16
  gemm_lds<0><<<dim3(96, 32), 256, 0, stream>>>(xb, wb, qkvb, 12288, 4096);
  // 3) gate = sigmoid(x @ w_gate^T), bf16
  gemm_lds<1><<<dim3(32, 32), 256, 0, stream>>>(xb, wb + nqkv, gateb, 4096, 4096);
  // 4) k^T, v^T per head
  transpose_kv<<<dim3(64, 4, 32), 256, 0, stream>>>(qkvb, kT, vT);
  // 5) per-block decayed KV contributions
  kv_blocks<<<dim3(16, 32), 256, 0, stream>>>(kT, vT, slope, MT);
  // 6) sequential-in-b scan -> per-block KV states
  kv_scan<<<dim3(2048), 256, 0, stream>>>(MT, kvc, slope, ST);
  // 7) attention outputs -> hidden
  attn_out<<<dim3(16, 32), 512, 0, stream>>>(qkvb, vT, ST, slope, hidden);
  // 8) RMSNorm * nw * gate -> bf16
  rms_gate<<<dim3(4096), 256, 0, stream>>>(hidden, gateb, nw, afinal);
  // 9) out = afinal @ w_out^T, fp32
  gemm_lds<2><<<dim3(32, 32), 256, 0, stream>>>(afinal, wob, out, 4096, 4096);
}